// Round 4
// baseline (539.707 us; speedup 1.0000x reference)
//
#include <hip/hip_runtime.h>
#include <hip/hip_bf16.h>

typedef __hip_bfloat16 bf16;
typedef __attribute__((ext_vector_type(8))) short bf16x8;
typedef __attribute__((ext_vector_type(4))) float f32x4;

#define S_LEN   2048
#define HIDDEN  5120
#define NHEADS  16
#define QLORA   1536
#define KVLORA  512
#define QKD     192
#define VD      128
#define QN      (NHEADS*QKD)          /* 3072 */
#define KVN     (NHEADS*(128+VD))     /* 4096 */
#define QCKN    2112                  /* 1536 qa | 512 ckv | 64 kpe */
#define SM_SCALE 0.07216878364870322f /* 192^-0.5 */

__device__ __forceinline__ f32x4 mfma16(bf16x8 a, bf16x8 b, f32x4 c) {
  return __builtin_amdgcn_mfma_f32_16x16x32_bf16(a, b, c, 0, 0, 0);
}
__device__ __forceinline__ void g2l16(const void* g, void* l) {
  __builtin_amdgcn_global_load_lds((const __attribute__((address_space(1))) void*)g,
                                   (__attribute__((address_space(3))) void*)l, 16, 0, 0);
}
__device__ __forceinline__ bf16x8 ld8(const bf16* p) { return *(const bf16x8*)p; }

// ---------------- fused fp32 -> bf16 cast over 5 weight segments ----------------
__global__ void cvt_multi(const float* s0, bf16* d0, int n0,
                          const float* s1, bf16* d1, int n1,
                          const float* s2, bf16* d2, int n2,
                          const float* s3, bf16* d3, int n3,
                          const float* s4, bf16* d4, int n4s)
{
  int i = blockIdx.x * 256 + threadIdx.x;
  const float* s; bf16* d;
  if (i < n0) { s = s0; d = d0; }
  else if ((i -= n0) < n1) { s = s1; d = d1; }
  else if ((i -= n1) < n2) { s = s2; d = d2; }
  else if ((i -= n2) < n3) { s = s3; d = d3; }
  else if ((i -= n3) < n4s) { s = s4; d = d4; }
  else return;
  const float4 v = ((const float4*)s)[i];
  union { bf16 b[4]; unsigned long long u; } pk;
  pk.b[0] = __float2bfloat16(v.x);
  pk.b[1] = __float2bfloat16(v.y);
  pk.b[2] = __float2bfloat16(v.z);
  pk.b[3] = __float2bfloat16(v.w);
  *(unsigned long long*)(d + (size_t)i * 4) = pk.u;
}

// ---------------- RMSNorm (fp32 in, bf16 out), one block per row ----------------
__global__ void rmsnorm_k(const float* __restrict__ in, int istride, int C,
                          const float* __restrict__ w,
                          bf16* __restrict__ out, int ostride)
{
  const int row = blockIdx.x;
  const float* x = in + (size_t)row * istride;
  float ss = 0.f;
  for (int c = threadIdx.x; c < C; c += 256) { float v = x[c]; ss += v * v; }
  #pragma unroll
  for (int m = 32; m >= 1; m >>= 1) ss += __shfl_xor(ss, m, 64);
  __shared__ float red[4];
  if ((threadIdx.x & 63) == 0) red[threadIdx.x >> 6] = ss;
  __syncthreads();
  ss = red[0] + red[1] + red[2] + red[3];
  const float sc = rsqrtf(ss / (float)C + 1e-6f);
  bf16* o = out + (size_t)row * ostride;
  for (int c = threadIdx.x; c < C; c += 256)
    o[c] = __float2bfloat16(x[c] * sc * w[c]);
}

// ---- fused dual RMSNorm over gemm1's 4 split-K PARTIALS (no atomics upstream):
__global__ void rmsnorm2_k(const float* __restrict__ parts,  // [4][S][2112]
                           const float* __restrict__ wq, const float* __restrict__ wk,
                           bf16* __restrict__ qa_n, bf16* __restrict__ ckv_n,
                           float* __restrict__ kpe_sum)      // [S][64]
{
  const int r = blockIdx.x;
  const bool is_q = r < S_LEN;
  const int row = is_q ? r : r - S_LEN;
  const int C = is_q ? QLORA : KVLORA;
  const size_t PS = (size_t)S_LEN * QCKN;
  const float* x0 = parts + (size_t)row * QCKN + (is_q ? 0 : QLORA);
  const float* w = is_q ? wq : wk;
  bf16* o = (is_q ? qa_n + (size_t)row * QLORA : ckv_n + (size_t)row * KVLORA);
  __shared__ float xs[QLORA];
  float ss = 0.f;
  for (int c = threadIdx.x; c < C; c += 256) {
    const float v = x0[c] + x0[PS + c] + x0[2 * PS + c] + x0[3 * PS + c];
    xs[c] = v;
    ss += v * v;
  }
  #pragma unroll
  for (int m = 32; m >= 1; m >>= 1) ss += __shfl_xor(ss, m, 64);
  __shared__ float red[4];
  if ((threadIdx.x & 63) == 0) red[threadIdx.x >> 6] = ss;
  __syncthreads();
  ss = red[0] + red[1] + red[2] + red[3];
  const float sc = rsqrtf(ss / (float)C + 1e-6f);
  for (int c = threadIdx.x; c < C; c += 256)
    o[c] = __float2bfloat16(xs[c] * sc * w[c]);
  if (!is_q) {
    const float* kp = parts + (size_t)row * QCKN + 2048;
    for (int c = threadIdx.x; c < 64; c += 256)
      kpe_sum[row * 64 + c] = kp[c] + kp[PS + c] + kp[2 * PS + c] + kp[3 * PS + c];
  }
}

// ---------------- NT GEMM, BK=64 (unchanged from r3) ----
template<bool RESID, bool CLAMPN, bool SPLIT>
__global__ __launch_bounds__(256, 4)
void gemm_nt(const bf16* __restrict__ A, const bf16* __restrict__ Bt,
             float* __restrict__ C, int M, int N, int lda, int klen,
             const float* __restrict__ resid, float rscale)
{
  __shared__ bf16 As[2 * 128 * 32];   // chunk-major: [c][row][32]
  __shared__ bf16 Bs[2 * 128 * 32];
  const int tid = threadIdx.x;
  const int wave = tid >> 6;
  const int lane = tid & 63;
  const int l15 = lane & 15, quad = lane >> 4;
  const int bm = blockIdx.x * 128, bn = blockIdx.y * 128;
  const int kbase = blockIdx.z * klen;
  const int wm = (wave >> 1) * 64, wn = (wave & 1) * 64;

  const int srow = tid >> 2;        // 0..63
  const int scol = (((tid & 3) ^ ((tid >> 3) & 3)) << 3);   // pre-swizzled source col
  const bf16* Ag0 = A + (size_t)(bm + srow) * lda + kbase + scol;
  const bf16* Ag1 = A + (size_t)(bm + 64 + srow) * lda + kbase + scol;
  int bn0 = bn + srow, bn1 = bn + 64 + srow;
  if (CLAMPN) { bn0 = min(bn0, N - 1); bn1 = min(bn1, N - 1); }
  const bf16* Bg0 = Bt + (size_t)bn0 * lda + kbase + scol;
  const bf16* Bg1 = Bt + (size_t)bn1 * lda + kbase + scol;

  char* AsW = (char*)As + wave * 1024;
  char* BsW = (char*)Bs + wave * 1024;

  const int qs = ((quad ^ ((l15 >> 1) & 3)) << 3);          // swizzled read col

  f32x4 acc[4][4];
  #pragma unroll
  for (int i = 0; i < 4; i++)
    #pragma unroll
    for (int j = 0; j < 4; j++) acc[i][j] = (f32x4){0.f, 0.f, 0.f, 0.f};

  const int nk = klen >> 6;
  for (int kt = 0; kt < nk; ++kt) {
    const int k0 = kt << 6;
    #pragma unroll
    for (int c = 0; c < 2; ++c) {
      g2l16(Ag0 + k0 + c * 32, AsW + c * 8192);
      g2l16(Ag1 + k0 + c * 32, AsW + c * 8192 + 4096);
      g2l16(Bg0 + k0 + c * 32, BsW + c * 8192);
      g2l16(Bg1 + k0 + c * 32, BsW + c * 8192 + 4096);
    }
    __syncthreads();
    #pragma unroll
    for (int c = 0; c < 2; ++c) {
      bf16x8 af[4], bfr[4];
      #pragma unroll
      for (int i = 0; i < 4; i++)
        af[i] = ld8(As + c * 4096 + (wm + i * 16 + l15) * 32 + qs);
      #pragma unroll
      for (int j = 0; j < 4; j++)
        bfr[j] = ld8(Bs + c * 4096 + (wn + j * 16 + l15) * 32 + qs);
      #pragma unroll
      for (int i = 0; i < 4; i++)
        #pragma unroll
        for (int j = 0; j < 4; j++)
          acc[i][j] = mfma16(af[i], bfr[j], acc[i][j]);
    }
    __syncthreads();
  }

  float* Cb = C;
  if (SPLIT) Cb += (size_t)blockIdx.z * ((size_t)S_LEN * (size_t)N);
  #pragma unroll
  for (int i = 0; i < 4; i++)
    #pragma unroll
    for (int j = 0; j < 4; j++) {
      const int row = bm + wm + i * 16 + quad * 4;
      const int col = bn + wn + j * 16 + l15;
      if (!CLAMPN || col < N) {
        #pragma unroll
        for (int r = 0; r < 4; r++) {
          float v = acc[i][j][r];
          const size_t idx = (size_t)(row + r) * N + col;
          if (RESID) v += resid[idx] * rscale;
          Cb[idx] = v;
        }
      }
    }
}

// ---------------- RoPE + assemble q/k (unchanged) ----------------
__global__ void rope_assemble_k(
    const float* __restrict__ qp,      // [2][S, 3072]
    const float* __restrict__ kpe_sum, // [S, 64]
    const float* __restrict__ kv,      // [S, 4096]
    const int*   __restrict__ pos,     // [S]
    float* __restrict__ k_out,         // [16,S,192]
    bf16*  __restrict__ q_bf,          // [16,S,192]
    bf16*  __restrict__ k_bf)          // [16,S,192]
{
  const int s = blockIdx.x;
  const int t = threadIdx.x;
  const size_t QPS = (size_t)S_LEN * QN;
  __shared__ float cs[32], sn[32], kpe[64];
  const float p = (float)pos[s];
  if (t < 32) {
    const float inv = powf(10000.0f, -((float)(2 * t)) / 64.0f);
    const float f = p * inv;
    float si, c;
    sincosf(f, &si, &c);
    cs[t] = c; sn[t] = si;
    const float r0v = kpe_sum[(size_t)s * 64 + 2 * t];
    const float r1v = kpe_sum[(size_t)s * 64 + 2 * t + 1];
    kpe[t]      = r0v * c - r1v * si;
    kpe[32 + t] = r1v * c + r0v * si;
  }
  __syncthreads();
  for (int i = t; i < NHEADS * 128; i += 256) {
    const int h = i >> 7, d = i & 127;
    const size_t o = ((size_t)h * S_LEN + s) * QKD + d;
    const float kn = kv[(size_t)s * KVN + h * 256 + d];
    k_out[o] = kn;
    k_bf[o] = __float2bfloat16(kn);
    const size_t qi = (size_t)s * QN + h * QKD + d;
    q_bf[o] = __float2bfloat16(qp[qi] + qp[QPS + qi]);
  }
  for (int i = t; i < NHEADS * 32; i += 256) {
    const int h = i >> 5, jj = i & 31;
    const size_t qi = (size_t)s * QN + h * QKD + 128 + 2 * jj;
    const float r0v = qp[qi] + qp[QPS + qi];
    const float r1v = qp[qi + 1] + qp[QPS + qi + 1];
    const float c = cs[jj], si = sn[jj];
    const size_t o = ((size_t)h * S_LEN + s) * QKD + 128;
    q_bf[o + jj]      = __float2bfloat16(r0v * c - r1v * si);
    q_bf[o + 32 + jj] = __float2bfloat16(r1v * c + r0v * si);
  }
  for (int i = t; i < NHEADS * 64; i += 256) {
    const int h = i >> 6, jj = i & 63;
    const float v = kpe[jj];
    const size_t o = ((size_t)h * S_LEN + s) * QKD + 128 + jj;
    k_out[o] = v;
    k_bf[o] = __float2bfloat16(v);
  }
}

// ---------------- V: fp32 out + bf16 transpose (unchanged) ----------------
__global__ void v_transpose_k(const float* __restrict__ kv,
                              float* __restrict__ v_out,
                              bf16* __restrict__ vt_bf)
{
  const int h = blockIdx.x, st = blockIdx.y, dt = blockIdx.z;
  __shared__ float tile[32][33];
  const int tx = threadIdx.x & 31;
  const int ty = (threadIdx.x >> 5) * 4;
  const int s0 = st * 32, d0 = dt * 32;
  #pragma unroll
  for (int r = 0; r < 4; r++) {
    const int sl = ty + r;
    const float v = kv[(size_t)(s0 + sl) * KVN + h * 256 + 128 + d0 + tx];
    v_out[((size_t)h * S_LEN + s0 + sl) * VD + d0 + tx] = v;
    tile[sl][tx] = v;
  }
  __syncthreads();
  #pragma unroll
  for (int r = 0; r < 4; r++) {
    const int dl = ty + r;
    vt_bf[((size_t)h * VD + d0 + dl) * S_LEN + s0 + tx] = __float2bfloat16(tile[tx][dl]);
  }
}

// ---------------- causal flash attention, PAIRED Q-tiles ----------------
// r4: load-balance fix. 512 variable-work blocks (1..32 units) -> 256 blocks
// each doing EXACTLY 33 work units: Q-tile LO (qt=b) + Q-tile HI (qt=31-b)
// share one K/V staging loop. 1 block/CU (XCD-pinned: 2 heads x 16 pairs per
// XCD), so no tail imbalance and no inter-block contention. K/V LDS fragments
// are read ONCE and feed both tiles' MFMAs (dual independent streams -> ILP).
// In the dual phase HI can't hit the diagonal (j<=15 < qth>=16) -> mask folds.
#define SMAX(Sx, mr, lr, Ox, r0x, slot, isdiag)                               \
  do {                                                                        \
    float mnew[4] = {-1e30f, -1e30f, -1e30f, -1e30f};                         \
    if (isdiag) {                                                             \
      _Pragma("unroll") for (int nt = 0; nt < 4; ++nt) {                      \
        const int col = kc + nt * 16 + l15;                                   \
        _Pragma("unroll") for (int r = 0; r < 4; r++) {                       \
          const int row = (r0x) + quad * 4 + r;                               \
          const float v = (col <= row) ? Sx[nt][r] * SM_SCALE : -1e30f;       \
          Sx[nt][r] = v; mnew[r] = fmaxf(mnew[r], v);                         \
        }                                                                     \
      }                                                                       \
    } else {                                                                  \
      _Pragma("unroll") for (int nt = 0; nt < 4; ++nt)                        \
        _Pragma("unroll") for (int r = 0; r < 4; r++) {                       \
          const float v = Sx[nt][r] * SM_SCALE;                               \
          Sx[nt][r] = v; mnew[r] = fmaxf(mnew[r], v);                         \
        }                                                                     \
    }                                                                         \
    _Pragma("unroll") for (int mm = 8; mm >= 1; mm >>= 1)                     \
      _Pragma("unroll") for (int r = 0; r < 4; r++)                           \
        mnew[r] = fmaxf(mnew[r], __shfl_xor(mnew[r], mm, 64));                \
    float alpha[4], ladd[4] = {0.f, 0.f, 0.f, 0.f};                           \
    _Pragma("unroll") for (int r = 0; r < 4; r++) {                           \
      const float mi = fmaxf(mr[r], mnew[r]);                                 \
      alpha[r] = __expf(mr[r] - mi); mr[r] = mi;                              \
    }                                                                         \
    _Pragma("unroll") for (int nt = 0; nt < 4; ++nt)                          \
      _Pragma("unroll") for (int r = 0; r < 4; r++) {                         \
        const float pv = __expf(Sx[nt][r] - mr[r]);                           \
        Sx[nt][r] = pv; ladd[r] += pv;                                        \
      }                                                                       \
    _Pragma("unroll") for (int mm = 8; mm >= 1; mm >>= 1)                     \
      _Pragma("unroll") for (int r = 0; r < 4; r++)                           \
        ladd[r] += __shfl_xor(ladd[r], mm, 64);                               \
    _Pragma("unroll") for (int r = 0; r < 4; r++)                             \
      lr[r] = lr[r] * alpha[r] + ladd[r];                                     \
    _Pragma("unroll") for (int d = 0; d < 8; ++d)                             \
      _Pragma("unroll") for (int r = 0; r < 4; r++) Ox[d][r] *= alpha[r];     \
    _Pragma("unroll") for (int nt = 0; nt < 4; ++nt)                          \
      _Pragma("unroll") for (int r = 0; r < 4; r++)                           \
        Plds[slot][wave][quad * 4 + r][nt * 16 + l15] =                       \
            __float2bfloat16(Sx[nt][r]);                                      \
  } while (0)

__global__ __launch_bounds__(256, 1)
void attn_k(const bf16* __restrict__ qb, const bf16* __restrict__ kb,
            const bf16* __restrict__ vt, bf16* __restrict__ aout)
{
  const int lin = blockIdx.x;                     // 256 blocks
  const int xcd = lin & 7;
  const int idx = lin >> 3;                       // 0..31
  const int head = xcd * 2 + (idx >> 4);
  const int b = idx & 15;                         // pair id
  const int qtl = b, qth = 31 - b;                // qth >= 16 > qtl
  const int wave = threadIdx.x >> 6, lane = threadIdx.x & 63;
  const int l15 = lane & 15, quad = lane >> 4;
  const int r0l = qtl * 64 + wave * 16;
  const int r0h = qth * 64 + wave * 16;

  const bf16* qh = qb + (size_t)head * S_LEN * QKD;
  const bf16* kh = kb + (size_t)head * S_LEN * QKD;
  const bf16* vh = vt + (size_t)head * VD * S_LEN;

  __shared__ bf16 Ks[6 * 64 * 32];
  __shared__ bf16 Vs[128 * 72];
  __shared__ bf16 Plds[2][4][16][72];

  const int tid = threadIdx.x;
  const int srow = wave * 16 + (lane >> 2);
  const int scol = (lane & 3) * 8;
  const bf16* ksrc = kh + (size_t)srow * QKD + scol;
  bf16* kdst = Ks + srow * 32 + (((lane & 3) ^ ((lane >> 3) & 3)) << 3);  // swz write
  const int vrow = tid >> 1;
  const int vcol = (tid & 1) * 32;
  const bf16* vsrc = vh + (size_t)vrow * S_LEN + vcol;
  bf16* vdst = Vs + vrow * 72 + vcol;

  const int qs = ((quad ^ ((l15 >> 1) & 3)) << 3);                        // swz read

  bf16x8 qfh[6], qfl[6];
  #pragma unroll
  for (int c = 0; c < 6; ++c) {
    qfh[c] = ld8(qh + (size_t)(r0h + l15) * QKD + c * 32 + quad * 8);
    qfl[c] = ld8(qh + (size_t)(r0l + l15) * QKD + c * 32 + quad * 8);
  }

  f32x4 Oh[8], Ol[8];
  #pragma unroll
  for (int d = 0; d < 8; ++d) {
    Oh[d] = (f32x4){0.f, 0.f, 0.f, 0.f};
    Ol[d] = (f32x4){0.f, 0.f, 0.f, 0.f};
  }
  float mh[4] = {-1e30f, -1e30f, -1e30f, -1e30f};
  float ml[4] = {-1e30f, -1e30f, -1e30f, -1e30f};
  float lh[4] = {0.f, 0.f, 0.f, 0.f};
  float ll[4] = {0.f, 0.f, 0.f, 0.f};

  bf16x8 kreg[6], vreg[4];
  #pragma unroll
  for (int c = 0; c < 6; ++c) kreg[c] = ld8(ksrc + c * 32);
  #pragma unroll
  for (int c = 0; c < 4; ++c) vreg[c] = ld8(vsrc + c * 8);

  for (int j = 0; j <= qth; ++j) {
    __syncthreads();
    #pragma unroll
    for (int c = 0; c < 6; ++c) *(bf16x8*)(kdst + c * 2048) = kreg[c];
    #pragma unroll
    for (int c = 0; c < 4; ++c) *(bf16x8*)(vdst + c * 8) = vreg[c];
    __syncthreads();
    if (j < qth) {
      const bf16* src = ksrc + (size_t)(j + 1) * 64 * QKD;
      #pragma unroll
      for (int c = 0; c < 6; ++c) kreg[c] = ld8(src + c * 32);
      const bf16* vs2 = vsrc + (size_t)(j + 1) * 64;
      #pragma unroll
      for (int c = 0; c < 4; ++c) vreg[c] = ld8(vs2 + c * 8);
    }
    const int kc = j * 64;

    if (j <= qtl) {
      // ---- dual phase: K/V fragments feed BOTH tiles ----
      f32x4 Sh[4], Sl[4];
      #pragma unroll
      for (int nt = 0; nt < 4; ++nt) {
        Sh[nt] = (f32x4){0.f, 0.f, 0.f, 0.f};
        Sl[nt] = (f32x4){0.f, 0.f, 0.f, 0.f};
      }
      #pragma unroll
      for (int c = 0; c < 6; ++c)
        #pragma unroll
        for (int nt = 0; nt < 4; ++nt) {
          const bf16x8 kf = ld8(Ks + c * 2048 + (nt * 16 + l15) * 32 + qs);
          Sh[nt] = mfma16(qfh[c], kf, Sh[nt]);
          Sl[nt] = mfma16(qfl[c], kf, Sl[nt]);
        }
      SMAX(Sh, mh, lh, Oh, r0h, 0, false);        // j<=15 < qth: never diag
      SMAX(Sl, ml, ll, Ol, r0l, 1, j == qtl);
      #pragma unroll
      for (int kt = 0; kt < 2; ++kt) {
        const bf16x8 pfh = ld8(&Plds[0][wave][l15][kt * 32 + quad * 8]);
        const bf16x8 pfl = ld8(&Plds[1][wave][l15][kt * 32 + quad * 8]);
        #pragma unroll
        for (int dt = 0; dt < 8; ++dt) {
          const bf16x8 vf = ld8(Vs + (dt * 16 + l15) * 72 + kt * 32 + quad * 8);
          Oh[dt] = mfma16(pfh, vf, Oh[dt]);
          Ol[dt] = mfma16(pfl, vf, Ol[dt]);
        }
      }
    } else {
      // ---- single phase: HI tile only ----
      f32x4 Sh[4];
      #pragma unroll
      for (int nt = 0; nt < 4; ++nt) Sh[nt] = (f32x4){0.f, 0.f, 0.f, 0.f};
      #pragma unroll
      for (int c = 0; c < 6; ++c)
        #pragma unroll
        for (int nt = 0; nt < 4; ++nt) {
          const bf16x8 kf = ld8(Ks + c * 2048 + (nt * 16 + l15) * 32 + qs);
          Sh[nt] = mfma16(qfh[c], kf, Sh[nt]);
        }
      SMAX(Sh, mh, lh, Oh, r0h, 0, j == qth);
      #pragma unroll
      for (int kt = 0; kt < 2; ++kt) {
        const bf16x8 pfh = ld8(&Plds[0][wave][l15][kt * 32 + quad * 8]);
        #pragma unroll
        for (int dt = 0; dt < 8; ++dt) {
          const bf16x8 vf = ld8(Vs + (dt * 16 + l15) * 72 + kt * 32 + quad * 8);
          Oh[dt] = mfma16(pfh, vf, Oh[dt]);
        }
      }
    }
  }

  #pragma unroll
  for (int dt = 0; dt < 8; ++dt) {
    const int col = head * VD + dt * 16 + l15;
    #pragma unroll
    for (int r = 0; r < 4; r++) {
      const int rowh = r0h + quad * 4 + r;
      const int rowl = r0l + quad * 4 + r;
      aout[(size_t)rowh * (NHEADS * VD) + col] = __float2bfloat16(Oh[dt][r] / lh[r]);
      aout[(size_t)rowl * (NHEADS * VD) + col] = __float2bfloat16(Ol[dt][r] / ll[r]);
    }
  }
}

// ---------------- host orchestration ----------------
extern "C" void kernel_launch(void* const* d_in, const int* in_sizes, int n_in,
                              void* d_out, int out_size, void* d_ws, size_t ws_size,
                              hipStream_t stream)
{
  const float* hs      = (const float*)d_in[0];
  const int*   pos     = (const int*)  d_in[1];
  const float* ln_w    = (const float*)d_in[3];
  const float* wq_a    = (const float*)d_in[4];
  const float* q_a_ln  = (const float*)d_in[5];
  const float* wq_b    = (const float*)d_in[6];
  const float* wkv_a   = (const float*)d_in[7];
  const float* kv_a_ln = (const float*)d_in[8];
  const float* wkv_b   = (const float*)d_in[9];
  const float* wo      = (const float*)d_in[10];

  float* out_hidden = (float*)d_out;
  float* out_k = out_hidden + (size_t)S_LEN * HIDDEN;
  float* out_v = out_k + (size_t)NHEADS * S_LEN * QKD;

  char* ws = (char*)d_ws;
  size_t off = 0;
  auto alloc = [&](size_t bytes) { char* p = ws + off; off += (bytes + 255) & ~255ULL; return p; };

  bf16* h_b     = (bf16*)alloc((size_t)S_LEN * HIDDEN * 2);
  bf16* w1_b    = (bf16*)alloc((size_t)QCKN * HIDDEN * 2);
  bf16* wqb_b   = (bf16*)alloc((size_t)QN * QLORA * 2);
  bf16* wkvb_b  = (bf16*)alloc((size_t)KVN * KVLORA * 2);
  bf16* wo_b    = (bf16*)alloc((size_t)HIDDEN * (NHEADS * VD) * 2);
  // scratch region reused twice:
  //   phase 1: gemm1 partials [4][S][2112] fp32            (69.2 MB)
  //   phase 2: q partials [2][S][3072] fp32 + kv_f [S][4096] fp32 (83.9 MB)
  char* region  = alloc((size_t)2 * S_LEN * QN * 4 + (size_t)S_LEN * KVN * 4);
  float* qa_parts = (float*)region;
  float* q_f      = (float*)region;                       // alias (after rmsnorm2)
  float* kv_f     = (float*)(region + (size_t)2 * S_LEN * QN * 4);
  float* kpe_sum = (float*)alloc((size_t)S_LEN * 64 * 4);
  bf16* qa_n    = (bf16*)alloc((size_t)S_LEN * QLORA * 2);
  bf16* ckv_n   = (bf16*)alloc((size_t)S_LEN * KVLORA * 2);
  bf16* q_bf    = (bf16*)alloc((size_t)NHEADS * S_LEN * QKD * 2);
  bf16* k_bf    = (bf16*)alloc((size_t)NHEADS * S_LEN * QKD * 2);
  bf16* vt_bf   = (bf16*)alloc((size_t)NHEADS * VD * S_LEN * 2);
  bf16* attn_b  = (bf16*)alloc((size_t)S_LEN * (NHEADS * VD) * 2);

  {
    const int n0 = (QLORA * HIDDEN) / 4;
    const int n1 = ((QCKN - QLORA) * HIDDEN) / 4;
    const int n2 = (QN * QLORA) / 4;
    const int n3 = (KVN * KVLORA) / 4;
    const int n4s = (HIDDEN * NHEADS * VD) / 4;
    const int tot = n0 + n1 + n2 + n3 + n4s;
    cvt_multi<<<(tot + 255) / 256, 256, 0, stream>>>(
        wq_a, w1_b, n0,
        wkv_a, w1_b + (size_t)QLORA * HIDDEN, n1,
        wq_b, wqb_b, n2,
        wkv_b, wkvb_b, n3,
        wo, wo_b, n4s);
  }

  rmsnorm_k<<<S_LEN, 256, 0, stream>>>(hs, HIDDEN, HIDDEN, ln_w, h_b, HIDDEN);

  // gemm1: [qa|ckv|kpe] partials = h @ w1^T  (split-K x4 -> 1088 blocks,
  // klen=1280, disjoint partial outputs, plain stores)
  gemm_nt<false, true, true><<<dim3(16, 17, 4), 256, 0, stream>>>(
      h_b, w1_b, qa_parts, S_LEN, QCKN, HIDDEN, HIDDEN / 4, nullptr, 0.f);

  // fused dual rmsnorm + 4-way partial reduction + kpe extraction
  rmsnorm2_k<<<2 * S_LEN, 256, 0, stream>>>(qa_parts, q_a_ln, kv_a_ln,
                                            qa_n, ckv_n, kpe_sum);

  // q partials = qa_n @ wq_b^T (split-K x2 -> 768 blocks, klen=768; reduction
  // fused into rope_assemble). Overwrites qa_parts region (dead now).
  gemm_nt<false, false, true><<<dim3(16, QN / 128, 2), 256, 0, stream>>>(
      qa_n, wqb_b, q_f, S_LEN, QN, QLORA, QLORA / 2, nullptr, 0.f);
  // kv = ckv_n @ wkv_b^T  (512 blocks, klen=512, plain store)
  gemm_nt<false, false, false><<<dim3(16, KVN / 128, 1), 256, 0, stream>>>(
      ckv_n, wkvb_b, kv_f, S_LEN, KVN, KVLORA, KVLORA, nullptr, 0.f);

  rope_assemble_k<<<S_LEN, 256, 0, stream>>>(q_f, kpe_sum, kv_f, pos,
                                             out_k, q_bf, k_bf);
  v_transpose_k<<<dim3(NHEADS, S_LEN / 32, VD / 32), 256, 0, stream>>>(kv_f, out_v, vt_bf);

  // paired causal attention: 256 blocks, 1/CU, 33 work units each
  attn_k<<<dim3(256), 256, 0, stream>>>(q_bf, k_bf, vt_bf, attn_b);

  // gemm4: out = attn @ wo^T + hs*0.125  (640 blocks, klen=2048, plain store)
  gemm_nt<true, false, false><<<dim3(16, HIDDEN / 128, 1), 256, 0, stream>>>(
      attn_b, wo_b, out_hidden, S_LEN, HIDDEN, NHEADS * VD, NHEADS * VD, hs, 0.125f);

  (void)in_sizes; (void)n_in; (void)out_size; (void)ws_size;
}

// Round 5
// 519.289 us; speedup vs baseline: 1.0393x; 1.0393x over previous
//
#include <hip/hip_runtime.h>
#include <hip/hip_bf16.h>

typedef __hip_bfloat16 bf16;
typedef __attribute__((ext_vector_type(8))) short bf16x8;
typedef __attribute__((ext_vector_type(4))) float f32x4;

#define S_LEN   2048
#define HIDDEN  5120
#define NHEADS  16
#define QLORA   1536
#define KVLORA  512
#define QKD     192
#define VD      128
#define QN      (NHEADS*QKD)          /* 3072 */
#define KVN     (NHEADS*(128+VD))     /* 4096 */
#define QCKN    2112                  /* 1536 qa | 512 ckv | 64 kpe */
#define SM_SCALE 0.07216878364870322f /* 192^-0.5 */

__device__ __forceinline__ f32x4 mfma16(bf16x8 a, bf16x8 b, f32x4 c) {
  return __builtin_amdgcn_mfma_f32_16x16x32_bf16(a, b, c, 0, 0, 0);
}
__device__ __forceinline__ void g2l16(const void* g, void* l) {
  __builtin_amdgcn_global_load_lds((const __attribute__((address_space(1))) void*)g,
                                   (__attribute__((address_space(3))) void*)l, 16, 0, 0);
}
__device__ __forceinline__ bf16x8 ld8(const bf16* p) { return *(const bf16x8*)p; }

// ---------------- fused fp32 -> bf16 cast over 5 weight segments ----------------
__global__ void cvt_multi(const float* s0, bf16* d0, int n0,
                          const float* s1, bf16* d1, int n1,
                          const float* s2, bf16* d2, int n2,
                          const float* s3, bf16* d3, int n3,
                          const float* s4, bf16* d4, int n4s)
{
  int i = blockIdx.x * 256 + threadIdx.x;
  const float* s; bf16* d;
  if (i < n0) { s = s0; d = d0; }
  else if ((i -= n0) < n1) { s = s1; d = d1; }
  else if ((i -= n1) < n2) { s = s2; d = d2; }
  else if ((i -= n2) < n3) { s = s3; d = d3; }
  else if ((i -= n3) < n4s) { s = s4; d = d4; }
  else return;
  const float4 v = ((const float4*)s)[i];
  union { bf16 b[4]; unsigned long long u; } pk;
  pk.b[0] = __float2bfloat16(v.x);
  pk.b[1] = __float2bfloat16(v.y);
  pk.b[2] = __float2bfloat16(v.z);
  pk.b[3] = __float2bfloat16(v.w);
  *(unsigned long long*)(d + (size_t)i * 4) = pk.u;
}

// ---------------- RMSNorm (fp32 in, bf16 out), one block per row ----------------
__global__ void rmsnorm_k(const float* __restrict__ in, int istride, int C,
                          const float* __restrict__ w,
                          bf16* __restrict__ out, int ostride)
{
  const int row = blockIdx.x;
  const float* x = in + (size_t)row * istride;
  float ss = 0.f;
  for (int c = threadIdx.x; c < C; c += 256) { float v = x[c]; ss += v * v; }
  #pragma unroll
  for (int m = 32; m >= 1; m >>= 1) ss += __shfl_xor(ss, m, 64);
  __shared__ float red[4];
  if ((threadIdx.x & 63) == 0) red[threadIdx.x >> 6] = ss;
  __syncthreads();
  ss = red[0] + red[1] + red[2] + red[3];
  const float sc = rsqrtf(ss / (float)C + 1e-6f);
  bf16* o = out + (size_t)row * ostride;
  for (int c = threadIdx.x; c < C; c += 256)
    o[c] = __float2bfloat16(x[c] * sc * w[c]);
}

// ---- fused dual RMSNorm over gemm1's 4 split-K PARTIALS (no atomics upstream):
__global__ void rmsnorm2_k(const float* __restrict__ parts,  // [4][S][2112]
                           const float* __restrict__ wq, const float* __restrict__ wk,
                           bf16* __restrict__ qa_n, bf16* __restrict__ ckv_n,
                           float* __restrict__ kpe_sum)      // [S][64]
{
  const int r = blockIdx.x;
  const bool is_q = r < S_LEN;
  const int row = is_q ? r : r - S_LEN;
  const int C = is_q ? QLORA : KVLORA;
  const size_t PS = (size_t)S_LEN * QCKN;
  const float* x0 = parts + (size_t)row * QCKN + (is_q ? 0 : QLORA);
  const float* w = is_q ? wq : wk;
  bf16* o = (is_q ? qa_n + (size_t)row * QLORA : ckv_n + (size_t)row * KVLORA);
  __shared__ float xs[QLORA];
  float ss = 0.f;
  for (int c = threadIdx.x; c < C; c += 256) {
    const float v = x0[c] + x0[PS + c] + x0[2 * PS + c] + x0[3 * PS + c];
    xs[c] = v;
    ss += v * v;
  }
  #pragma unroll
  for (int m = 32; m >= 1; m >>= 1) ss += __shfl_xor(ss, m, 64);
  __shared__ float red[4];
  if ((threadIdx.x & 63) == 0) red[threadIdx.x >> 6] = ss;
  __syncthreads();
  ss = red[0] + red[1] + red[2] + red[3];
  const float sc = rsqrtf(ss / (float)C + 1e-6f);
  for (int c = threadIdx.x; c < C; c += 256)
    o[c] = __float2bfloat16(xs[c] * sc * w[c]);
  if (!is_q) {
    const float* kp = parts + (size_t)row * QCKN + 2048;
    for (int c = threadIdx.x; c < 64; c += 256)
      kpe_sum[row * 64 + c] = kp[c] + kp[PS + c] + kp[2 * PS + c] + kp[3 * PS + c];
  }
}

// ---------------- NT GEMM, BK=64 (unchanged from r3) ----
template<bool RESID, bool CLAMPN, bool SPLIT>
__global__ __launch_bounds__(256, 4)
void gemm_nt(const bf16* __restrict__ A, const bf16* __restrict__ Bt,
             float* __restrict__ C, int M, int N, int lda, int klen,
             const float* __restrict__ resid, float rscale)
{
  __shared__ bf16 As[2 * 128 * 32];   // chunk-major: [c][row][32]
  __shared__ bf16 Bs[2 * 128 * 32];
  const int tid = threadIdx.x;
  const int wave = tid >> 6;
  const int lane = tid & 63;
  const int l15 = lane & 15, quad = lane >> 4;
  const int bm = blockIdx.x * 128, bn = blockIdx.y * 128;
  const int kbase = blockIdx.z * klen;
  const int wm = (wave >> 1) * 64, wn = (wave & 1) * 64;

  const int srow = tid >> 2;        // 0..63
  const int scol = (((tid & 3) ^ ((tid >> 3) & 3)) << 3);   // pre-swizzled source col
  const bf16* Ag0 = A + (size_t)(bm + srow) * lda + kbase + scol;
  const bf16* Ag1 = A + (size_t)(bm + 64 + srow) * lda + kbase + scol;
  int bn0 = bn + srow, bn1 = bn + 64 + srow;
  if (CLAMPN) { bn0 = min(bn0, N - 1); bn1 = min(bn1, N - 1); }
  const bf16* Bg0 = Bt + (size_t)bn0 * lda + kbase + scol;
  const bf16* Bg1 = Bt + (size_t)bn1 * lda + kbase + scol;

  char* AsW = (char*)As + wave * 1024;
  char* BsW = (char*)Bs + wave * 1024;

  const int qs = ((quad ^ ((l15 >> 1) & 3)) << 3);          // swizzled read col

  f32x4 acc[4][4];
  #pragma unroll
  for (int i = 0; i < 4; i++)
    #pragma unroll
    for (int j = 0; j < 4; j++) acc[i][j] = (f32x4){0.f, 0.f, 0.f, 0.f};

  const int nk = klen >> 6;
  for (int kt = 0; kt < nk; ++kt) {
    const int k0 = kt << 6;
    #pragma unroll
    for (int c = 0; c < 2; ++c) {
      g2l16(Ag0 + k0 + c * 32, AsW + c * 8192);
      g2l16(Ag1 + k0 + c * 32, AsW + c * 8192 + 4096);
      g2l16(Bg0 + k0 + c * 32, BsW + c * 8192);
      g2l16(Bg1 + k0 + c * 32, BsW + c * 8192 + 4096);
    }
    __syncthreads();
    #pragma unroll
    for (int c = 0; c < 2; ++c) {
      bf16x8 af[4], bfr[4];
      #pragma unroll
      for (int i = 0; i < 4; i++)
        af[i] = ld8(As + c * 4096 + (wm + i * 16 + l15) * 32 + qs);
      #pragma unroll
      for (int j = 0; j < 4; j++)
        bfr[j] = ld8(Bs + c * 4096 + (wn + j * 16 + l15) * 32 + qs);
      #pragma unroll
      for (int i = 0; i < 4; i++)
        #pragma unroll
        for (int j = 0; j < 4; j++)
          acc[i][j] = mfma16(af[i], bfr[j], acc[i][j]);
    }
    __syncthreads();
  }

  float* Cb = C;
  if (SPLIT) Cb += (size_t)blockIdx.z * ((size_t)S_LEN * (size_t)N);
  #pragma unroll
  for (int i = 0; i < 4; i++)
    #pragma unroll
    for (int j = 0; j < 4; j++) {
      const int row = bm + wm + i * 16 + quad * 4;
      const int col = bn + wn + j * 16 + l15;
      if (!CLAMPN || col < N) {
        #pragma unroll
        for (int r = 0; r < 4; r++) {
          float v = acc[i][j][r];
          const size_t idx = (size_t)(row + r) * N + col;
          if (RESID) v += resid[idx] * rscale;
          Cb[idx] = v;
        }
      }
    }
}

// ---------------- RoPE + assemble q/k (unchanged) ----------------
__global__ void rope_assemble_k(
    const float* __restrict__ qp,      // [2][S, 3072]
    const float* __restrict__ kpe_sum, // [S, 64]
    const float* __restrict__ kv,      // [S, 4096]
    const int*   __restrict__ pos,     // [S]
    float* __restrict__ k_out,         // [16,S,192]
    bf16*  __restrict__ q_bf,          // [16,S,192]
    bf16*  __restrict__ k_bf)          // [16,S,192]
{
  const int s = blockIdx.x;
  const int t = threadIdx.x;
  const size_t QPS = (size_t)S_LEN * QN;
  __shared__ float cs[32], sn[32], kpe[64];
  const float p = (float)pos[s];
  if (t < 32) {
    const float inv = powf(10000.0f, -((float)(2 * t)) / 64.0f);
    const float f = p * inv;
    float si, c;
    sincosf(f, &si, &c);
    cs[t] = c; sn[t] = si;
    const float r0v = kpe_sum[(size_t)s * 64 + 2 * t];
    const float r1v = kpe_sum[(size_t)s * 64 + 2 * t + 1];
    kpe[t]      = r0v * c - r1v * si;
    kpe[32 + t] = r1v * c + r0v * si;
  }
  __syncthreads();
  for (int i = t; i < NHEADS * 128; i += 256) {
    const int h = i >> 7, d = i & 127;
    const size_t o = ((size_t)h * S_LEN + s) * QKD + d;
    const float kn = kv[(size_t)s * KVN + h * 256 + d];
    k_out[o] = kn;
    k_bf[o] = __float2bfloat16(kn);
    const size_t qi = (size_t)s * QN + h * QKD + d;
    q_bf[o] = __float2bfloat16(qp[qi] + qp[QPS + qi]);
  }
  for (int i = t; i < NHEADS * 32; i += 256) {
    const int h = i >> 5, jj = i & 31;
    const size_t qi = (size_t)s * QN + h * QKD + 128 + 2 * jj;
    const float r0v = qp[qi] + qp[QPS + qi];
    const float r1v = qp[qi + 1] + qp[QPS + qi + 1];
    const float c = cs[jj], si = sn[jj];
    const size_t o = ((size_t)h * S_LEN + s) * QKD + 128;
    q_bf[o + jj]      = __float2bfloat16(r0v * c - r1v * si);
    q_bf[o + 32 + jj] = __float2bfloat16(r1v * c + r0v * si);
  }
  for (int i = t; i < NHEADS * 64; i += 256) {
    const int h = i >> 6, jj = i & 63;
    const float v = kpe[jj];
    const size_t o = ((size_t)h * S_LEN + s) * QKD + 128 + jj;
    k_out[o] = v;
    k_bf[o] = __float2bfloat16(v);
  }
}

// ---------------- V: fp32 out + bf16 transpose (unchanged) ----------------
__global__ void v_transpose_k(const float* __restrict__ kv,
                              float* __restrict__ v_out,
                              bf16* __restrict__ vt_bf)
{
  const int h = blockIdx.x, st = blockIdx.y, dt = blockIdx.z;
  __shared__ float tile[32][33];
  const int tx = threadIdx.x & 31;
  const int ty = (threadIdx.x >> 5) * 4;
  const int s0 = st * 32, d0 = dt * 32;
  #pragma unroll
  for (int r = 0; r < 4; r++) {
    const int sl = ty + r;
    const float v = kv[(size_t)(s0 + sl) * KVN + h * 256 + 128 + d0 + tx];
    v_out[((size_t)h * S_LEN + s0 + sl) * VD + d0 + tx] = v;
    tile[sl][tx] = v;
  }
  __syncthreads();
  #pragma unroll
  for (int r = 0; r < 4; r++) {
    const int dl = ty + r;
    vt_bf[((size_t)h * VD + d0 + dl) * S_LEN + s0 + tx] = __float2bfloat16(tile[tx][dl]);
  }
}

// ---------------- causal flash attention: balanced split + merge ----------------
// r5: TLP fix. r4's 256 blocks = 1 block/CU = 1 wave/SIMD -> ~65% latency
// stall (occupancy counter 10.4%). Split each 33-unit pair over TWO blocks:
//   role A (16 units): HI tile (qt=31-b), j in [0,16)  -> partial (O,m,l)
//   role B (17 units): LO tile full (direct out) + HI j in [16,qth] -> partial
// 512 balanced blocks -> 2 blocks/CU resident (LDS 2x52KB=104KB, VGPR<256,
// launch_bounds(256,2)) = 2 waves/SIMD interleave. merge_k combines HI partials.
template<bool PARTIAL>
__device__ __forceinline__ void attn_tile(
    const bf16* __restrict__ qh, const bf16* __restrict__ kh,
    const bf16* __restrict__ vh,
    bf16* Ks, bf16* Vs, bf16* Plds,
    int qt, int j0, int j1, int head,
    bf16* __restrict__ aout, float* __restrict__ Op, float* __restrict__ Ml)
{
  const int tid = threadIdx.x;
  const int wave = tid >> 6, lane = tid & 63;
  const int l15 = lane & 15, quad = lane >> 4;
  const int r0 = qt * 64 + wave * 16;

  const int srow = wave * 16 + (lane >> 2);
  const int scol = (lane & 3) * 8;
  const bf16* ksrc = kh + (size_t)srow * QKD + scol;
  bf16* kdst = Ks + srow * 32 + (((lane & 3) ^ ((lane >> 3) & 3)) << 3);  // swz write
  const int vrow = tid >> 1;
  const int vcol = (tid & 1) * 32;
  const bf16* vsrc = vh + (size_t)vrow * S_LEN + vcol;
  bf16* vdst = Vs + vrow * 72 + vcol;
  const int qs = ((quad ^ ((l15 >> 1) & 3)) << 3);                        // swz read

  bf16x8 qf[6];
  #pragma unroll
  for (int c = 0; c < 6; ++c)
    qf[c] = ld8(qh + (size_t)(r0 + l15) * QKD + c * 32 + quad * 8);

  f32x4 O[8];
  #pragma unroll
  for (int d = 0; d < 8; ++d) O[d] = (f32x4){0.f, 0.f, 0.f, 0.f};
  float mrow[4] = {-1e30f, -1e30f, -1e30f, -1e30f};
  float lrow[4] = {0.f, 0.f, 0.f, 0.f};

  bf16x8 kreg[6], vreg[4];
  #pragma unroll
  for (int c = 0; c < 6; ++c) kreg[c] = ld8(ksrc + (size_t)j0 * 64 * QKD + c * 32);
  #pragma unroll
  for (int c = 0; c < 4; ++c) vreg[c] = ld8(vsrc + (size_t)j0 * 64 + c * 8);

  for (int j = j0; j < j1; ++j) {
    __syncthreads();
    #pragma unroll
    for (int c = 0; c < 6; ++c) *(bf16x8*)(kdst + c * 2048) = kreg[c];
    #pragma unroll
    for (int c = 0; c < 4; ++c) *(bf16x8*)(vdst + c * 8) = vreg[c];
    __syncthreads();
    if (j + 1 < j1) {
      const bf16* src = ksrc + (size_t)(j + 1) * 64 * QKD;
      #pragma unroll
      for (int c = 0; c < 6; ++c) kreg[c] = ld8(src + c * 32);
      const bf16* vs2 = vsrc + (size_t)(j + 1) * 64;
      #pragma unroll
      for (int c = 0; c < 4; ++c) vreg[c] = ld8(vs2 + c * 8);
    }
    const int kc = j * 64;

    f32x4 S[4];
    #pragma unroll
    for (int nt = 0; nt < 4; ++nt) S[nt] = (f32x4){0.f, 0.f, 0.f, 0.f};
    #pragma unroll
    for (int c = 0; c < 6; ++c)
      #pragma unroll
      for (int nt = 0; nt < 4; ++nt) {
        const bf16x8 kf = ld8(Ks + c * 2048 + (nt * 16 + l15) * 32 + qs);
        S[nt] = mfma16(qf[c], kf, S[nt]);
      }

    float mnew[4] = {-1e30f, -1e30f, -1e30f, -1e30f};
    if (j == qt) {
      #pragma unroll
      for (int nt = 0; nt < 4; ++nt) {
        const int col = kc + nt * 16 + l15;
        #pragma unroll
        for (int r = 0; r < 4; r++) {
          const int row = r0 + quad * 4 + r;
          const float v = (col <= row) ? S[nt][r] * SM_SCALE : -1e30f;
          S[nt][r] = v;
          mnew[r] = fmaxf(mnew[r], v);
        }
      }
    } else {
      #pragma unroll
      for (int nt = 0; nt < 4; ++nt)
        #pragma unroll
        for (int r = 0; r < 4; r++) {
          const float v = S[nt][r] * SM_SCALE;
          S[nt][r] = v;
          mnew[r] = fmaxf(mnew[r], v);
        }
    }
    #pragma unroll
    for (int m = 8; m >= 1; m >>= 1)
      #pragma unroll
      for (int r = 0; r < 4; r++)
        mnew[r] = fmaxf(mnew[r], __shfl_xor(mnew[r], m, 64));
    float alpha[4], ladd[4] = {0.f, 0.f, 0.f, 0.f};
    #pragma unroll
    for (int r = 0; r < 4; r++) {
      const float mi = fmaxf(mrow[r], mnew[r]);
      alpha[r] = __expf(mrow[r] - mi);
      mrow[r] = mi;
    }
    #pragma unroll
    for (int nt = 0; nt < 4; ++nt)
      #pragma unroll
      for (int r = 0; r < 4; r++) {
        const float pv = __expf(S[nt][r] - mrow[r]);
        S[nt][r] = pv;
        ladd[r] += pv;
      }
    #pragma unroll
    for (int m = 8; m >= 1; m >>= 1)
      #pragma unroll
      for (int r = 0; r < 4; r++) ladd[r] += __shfl_xor(ladd[r], m, 64);
    #pragma unroll
    for (int r = 0; r < 4; r++) lrow[r] = lrow[r] * alpha[r] + ladd[r];
    #pragma unroll
    for (int d = 0; d < 8; ++d)
      #pragma unroll
      for (int r = 0; r < 4; r++) O[d][r] *= alpha[r];

    #pragma unroll
    for (int nt = 0; nt < 4; ++nt)
      #pragma unroll
      for (int r = 0; r < 4; r++)
        Plds[(wave * 16 + quad * 4 + r) * 72 + nt * 16 + l15] =
            __float2bfloat16(S[nt][r]);

    #pragma unroll
    for (int kt = 0; kt < 2; ++kt) {
      const bf16x8 pf = ld8(Plds + (wave * 16 + l15) * 72 + kt * 32 + quad * 8);
      #pragma unroll
      for (int dt = 0; dt < 8; ++dt) {
        const bf16x8 vf = ld8(Vs + (dt * 16 + l15) * 72 + kt * 32 + quad * 8);
        O[dt] = mfma16(pf, vf, O[dt]);
      }
    }
  }

  if (PARTIAL) {
    #pragma unroll
    for (int dt = 0; dt < 8; ++dt)
      #pragma unroll
      for (int r = 0; r < 4; r++)
        Op[(wave * 16 + quad * 4 + r) * 128 + dt * 16 + l15] = O[dt][r];
    if (l15 == 0) {
      #pragma unroll
      for (int r = 0; r < 4; r++) {
        Ml[wave * 16 + quad * 4 + r] = mrow[r];
        Ml[64 + wave * 16 + quad * 4 + r] = lrow[r];
      }
    }
  } else {
    #pragma unroll
    for (int dt = 0; dt < 8; ++dt) {
      const int col = head * VD + dt * 16 + l15;
      #pragma unroll
      for (int r = 0; r < 4; r++) {
        const int row = r0 + quad * 4 + r;
        aout[(size_t)row * (NHEADS * VD) + col] = __float2bfloat16(O[dt][r] / lrow[r]);
      }
    }
  }
}

__global__ __launch_bounds__(256, 2)
void attn_k(const bf16* __restrict__ qb, const bf16* __restrict__ kb,
            const bf16* __restrict__ vt, bf16* __restrict__ aout,
            float* __restrict__ Opart, float* __restrict__ Mlpart)
{
  __shared__ bf16 Ks[6 * 64 * 32];
  __shared__ bf16 Vs[128 * 72];
  __shared__ bf16 Plds[4 * 16 * 72];

  const int lin = blockIdx.x;                 // 512 blocks
  const int xcd = lin & 7;
  const int t = lin >> 3;                     // 0..63
  const int head = xcd * 2 + (t >> 5);
  const int rem = t & 31;
  const int b = rem >> 1;                     // pair id 0..15
  const int role = rem & 1;
  const int qtl = b, qth = 31 - b;
  const int pi = head * 16 + (15 - b);        // HI tile index 0..255

  const bf16* qh = qb + (size_t)head * S_LEN * QKD;
  const bf16* kh = kb + (size_t)head * S_LEN * QKD;
  const bf16* vh = vt + (size_t)head * VD * S_LEN;

  if (role == 0) {
    attn_tile<true>(qh, kh, vh, Ks, Vs, Plds, qth, 0, 16, head, aout,
                    Opart + (size_t)pi * 8192, Mlpart + (size_t)pi * 128);
  } else {
    attn_tile<false>(qh, kh, vh, Ks, Vs, Plds, qtl, 0, qtl + 1, head, aout,
                     nullptr, nullptr);
    attn_tile<true>(qh, kh, vh, Ks, Vs, Plds, qth, 16, qth + 1, head, aout,
                    Opart + (size_t)(256 + pi) * 8192,
                    Mlpart + (size_t)(256 + pi) * 128);
  }
}

// ---------------- merge the two HI partials per tile ----------------
__global__ void merge_k(const float* __restrict__ Opart,
                        const float* __restrict__ Mlpart,
                        bf16* __restrict__ aout)
{
  const int pi = blockIdx.x;              // 0..255
  const int head = pi >> 4;
  const int qth = (pi & 15) + 16;
  const int tid = threadIdx.x;            // 256
  const int r = tid >> 2;                 // row 0..63
  const int d0 = (tid & 3) * 32;
  const float mA = Mlpart[(size_t)pi * 128 + r];
  const float lA = Mlpart[(size_t)pi * 128 + 64 + r];
  const float mB = Mlpart[(size_t)(256 + pi) * 128 + r];
  const float lB = Mlpart[(size_t)(256 + pi) * 128 + 64 + r];
  const float m = fmaxf(mA, mB);
  const float fa = __expf(mA - m), fb = __expf(mB - m);
  const float inv = 1.f / (lA * fa + lB * fb);
  const float4* OA = (const float4*)(Opart + (size_t)pi * 8192 + r * 128 + d0);
  const float4* OB = (const float4*)(Opart + (size_t)(256 + pi) * 8192 + r * 128 + d0);
  bf16* out = aout + (size_t)(qth * 64 + r) * (NHEADS * VD) + head * VD + d0;
  #pragma unroll
  for (int i = 0; i < 8; ++i) {
    const float4 va = OA[i], vb = OB[i];
    union { bf16 h[4]; unsigned long long u; } pk;
    pk.h[0] = __float2bfloat16((va.x * fa + vb.x * fb) * inv);
    pk.h[1] = __float2bfloat16((va.y * fa + vb.y * fb) * inv);
    pk.h[2] = __float2bfloat16((va.z * fa + vb.z * fb) * inv);
    pk.h[3] = __float2bfloat16((va.w * fa + vb.w * fb) * inv);
    *(unsigned long long*)(out + i * 4) = pk.u;
  }
}

// ---------------- host orchestration ----------------
extern "C" void kernel_launch(void* const* d_in, const int* in_sizes, int n_in,
                              void* d_out, int out_size, void* d_ws, size_t ws_size,
                              hipStream_t stream)
{
  const float* hs      = (const float*)d_in[0];
  const int*   pos     = (const int*)  d_in[1];
  const float* ln_w    = (const float*)d_in[3];
  const float* wq_a    = (const float*)d_in[4];
  const float* q_a_ln  = (const float*)d_in[5];
  const float* wq_b    = (const float*)d_in[6];
  const float* wkv_a   = (const float*)d_in[7];
  const float* kv_a_ln = (const float*)d_in[8];
  const float* wkv_b   = (const float*)d_in[9];
  const float* wo      = (const float*)d_in[10];

  float* out_hidden = (float*)d_out;
  float* out_k = out_hidden + (size_t)S_LEN * HIDDEN;
  float* out_v = out_k + (size_t)NHEADS * S_LEN * QKD;

  char* ws = (char*)d_ws;
  size_t off = 0;
  auto alloc = [&](size_t bytes) { char* p = ws + off; off += (bytes + 255) & ~255ULL; return p; };

  bf16* h_b     = (bf16*)alloc((size_t)S_LEN * HIDDEN * 2);
  bf16* w1_b    = (bf16*)alloc((size_t)QCKN * HIDDEN * 2);
  bf16* wqb_b   = (bf16*)alloc((size_t)QN * QLORA * 2);
  bf16* wkvb_b  = (bf16*)alloc((size_t)KVN * KVLORA * 2);
  bf16* wo_b    = (bf16*)alloc((size_t)HIDDEN * (NHEADS * VD) * 2);
  // scratch region reused 3x:
  //   phase 1: gemm1 partials [4][S][2112] fp32            (69.2 MB)
  //   phase 2: q partials [2][S][3072] fp32 + kv_f [S][4096] fp32 (83.9 MB)
  //   phase 3 (attn): HI-tile softmax partials Opart/Mlpart (17.1 MB)
  char* region  = alloc((size_t)2 * S_LEN * QN * 4 + (size_t)S_LEN * KVN * 4);
  float* qa_parts = (float*)region;
  float* q_f      = (float*)region;                       // alias (after rmsnorm2)
  float* kv_f     = (float*)(region + (size_t)2 * S_LEN * QN * 4);
  float* Opart    = (float*)region;                       // alias (after v_transpose)
  float* Mlpart   = (float*)(region + (size_t)512 * 8192 * 4);
  float* kpe_sum = (float*)alloc((size_t)S_LEN * 64 * 4);
  bf16* qa_n    = (bf16*)alloc((size_t)S_LEN * QLORA * 2);
  bf16* ckv_n   = (bf16*)alloc((size_t)S_LEN * KVLORA * 2);
  bf16* q_bf    = (bf16*)alloc((size_t)NHEADS * S_LEN * QKD * 2);
  bf16* k_bf    = (bf16*)alloc((size_t)NHEADS * S_LEN * QKD * 2);
  bf16* vt_bf   = (bf16*)alloc((size_t)NHEADS * VD * S_LEN * 2);
  bf16* attn_b  = (bf16*)alloc((size_t)S_LEN * (NHEADS * VD) * 2);

  {
    const int n0 = (QLORA * HIDDEN) / 4;
    const int n1 = ((QCKN - QLORA) * HIDDEN) / 4;
    const int n2 = (QN * QLORA) / 4;
    const int n3 = (KVN * KVLORA) / 4;
    const int n4s = (HIDDEN * NHEADS * VD) / 4;
    const int tot = n0 + n1 + n2 + n3 + n4s;
    cvt_multi<<<(tot + 255) / 256, 256, 0, stream>>>(
        wq_a, w1_b, n0,
        wkv_a, w1_b + (size_t)QLORA * HIDDEN, n1,
        wq_b, wqb_b, n2,
        wkv_b, wkvb_b, n3,
        wo, wo_b, n4s);
  }

  rmsnorm_k<<<S_LEN, 256, 0, stream>>>(hs, HIDDEN, HIDDEN, ln_w, h_b, HIDDEN);

  // gemm1: [qa|ckv|kpe] partials = h @ w1^T  (split-K x4 -> 1088 blocks,
  // klen=1280, disjoint partial outputs, plain stores)
  gemm_nt<false, true, true><<<dim3(16, 17, 4), 256, 0, stream>>>(
      h_b, w1_b, qa_parts, S_LEN, QCKN, HIDDEN, HIDDEN / 4, nullptr, 0.f);

  // fused dual rmsnorm + 4-way partial reduction + kpe extraction
  rmsnorm2_k<<<2 * S_LEN, 256, 0, stream>>>(qa_parts, q_a_ln, kv_a_ln,
                                            qa_n, ckv_n, kpe_sum);

  // q partials = qa_n @ wq_b^T (split-K x2 -> 768 blocks, klen=768; reduction
  // fused into rope_assemble). Overwrites qa_parts region (dead now).
  gemm_nt<false, false, true><<<dim3(16, QN / 128, 2), 256, 0, stream>>>(
      qa_n, wqb_b, q_f, S_LEN, QN, QLORA, QLORA / 2, nullptr, 0.f);
  // kv = ckv_n @ wkv_b^T  (512 blocks, klen=512, plain store)
  gemm_nt<false, false, false><<<dim3(16, KVN / 128, 1), 256, 0, stream>>>(
      ckv_n, wkvb_b, kv_f, S_LEN, KVN, KVLORA, KVLORA, nullptr, 0.f);

  rope_assemble_k<<<S_LEN, 256, 0, stream>>>(q_f, kpe_sum, kv_f, pos,
                                             out_k, q_bf, k_bf);
  v_transpose_k<<<dim3(NHEADS, S_LEN / 32, VD / 32), 256, 0, stream>>>(kv_f, out_v, vt_bf);

  // balanced split attention: 512 blocks (2/CU), roles A=16 / B=17 units
  attn_k<<<dim3(512), 256, 0, stream>>>(q_bf, k_bf, vt_bf, attn_b, Opart, Mlpart);
  merge_k<<<dim3(256), 256, 0, stream>>>(Opart, Mlpart, attn_b);

  // gemm4: out = attn @ wo^T + hs*0.125  (640 blocks, klen=2048, plain store)
  gemm_nt<true, false, false><<<dim3(16, HIDDEN / 128, 1), 256, 0, stream>>>(
      attn_b, wo_b, out_hidden, S_LEN, HIDDEN, NHEADS * VD, NHEADS * VD, hs, 0.125f);

  (void)in_sizes; (void)n_in; (void)out_size; (void)ws_size;
}